// Round 2
// baseline (245.635 us; speedup 1.0000x reference)
//
#include <hip/hip_runtime.h>

#define NROW 4096
#define DIM  1024
#define TEMP_INV 14.285714285714286f /* 1/0.07 */

typedef __attribute__((ext_vector_type(8))) short bf16x8;
typedef __attribute__((ext_vector_type(4))) float f32x4;

__device__ __forceinline__ unsigned f2bf_u(float f) {
  unsigned u = __float_as_uint(f);
  return (u + 0x7FFFu + ((u >> 16) & 1u)) >> 16;  // RNE bf16
}

__device__ __forceinline__ float wave_sum_f(float v) {
#pragma unroll
  for (int off = 32; off > 0; off >>= 1) v += __shfl_down(v, off);
  return v;
}

__device__ __forceinline__ unsigned mono_key(float x) {
  unsigned u = __float_as_uint(x);
  return (u & 0x80000000u) ? ~u : (u | 0x80000000u);
}
__device__ __forceinline__ float inv_key(unsigned k) {
  return __uint_as_float((k & 0x80000000u) ? (k ^ 0x80000000u) : ~k);
}

// ---------------- Kernel 1: L2 normalize rows, emit bf16 ----------------
__global__ __launch_bounds__(256) void normalize_k(const float* __restrict__ X,
                                                   unsigned short* __restrict__ FB) {
  __shared__ float warp_s[4];
  const int row = blockIdx.x;
  const int tid = threadIdx.x;
  const float4* x4 = (const float4*)(X + (size_t)row * DIM);
  float4 v = x4[tid];  // 256 threads * 4 = 1024
  float ss = v.x * v.x + v.y * v.y + v.z * v.z + v.w * v.w;
  ss = wave_sum_f(ss);
  if ((tid & 63) == 0) warp_s[tid >> 6] = ss;
  __syncthreads();
  float total = warp_s[0] + warp_s[1] + warp_s[2] + warp_s[3];
  float inv = 1.0f / fmaxf(sqrtf(total), 1e-12f);
  ushort4 o;
  o.x = (unsigned short)f2bf_u(v.x * inv);
  o.y = (unsigned short)f2bf_u(v.y * inv);
  o.z = (unsigned short)f2bf_u(v.z * inv);
  o.w = (unsigned short)f2bf_u(v.w * inv);
  ((ushort4*)(FB + (size_t)row * DIM))[tid] = o;
}

// ---------------- Kernel 2: sim = (FB @ FB^T) * (1/T), f32 out ----------------
// 128x128 tile, BK=32, 4 waves each owning a 64x64 subtile, 16x16x32 bf16 MFMA.
__global__ __launch_bounds__(256) void gemm_sim(const unsigned short* __restrict__ FB,
                                                float* __restrict__ C) {
  __shared__ unsigned short As[128 * 32] __attribute__((aligned(16)));
  __shared__ unsigned short Bs[128 * 32] __attribute__((aligned(16)));
  const int tid  = threadIdx.x;
  const int wave = tid >> 6;
  const int lane = tid & 63;
  const int wr = wave >> 1;  // wave row 0..1
  const int wc = wave & 1;   // wave col 0..1
  const int brow = blockIdx.y * 128;
  const int bcol = blockIdx.x * 128;

  f32x4 acc[4][4];
#pragma unroll
  for (int m = 0; m < 4; ++m)
#pragma unroll
    for (int n = 0; n < 4; ++n) acc[m][n] = (f32x4){0.f, 0.f, 0.f, 0.f};

  // staging geometry: instruction t in {0,1} covers rows t*64 + wave*16 + (lane>>2),
  // cols (lane&3)*8 .. +8; LDS dest = linear, wave-uniform base + lane*16B.
  const int s_r = wave * 16 + (lane >> 2);
  const int s_c = (lane & 3) * 8;
  unsigned short* ldsA0 = As + wave * 512;
  unsigned short* ldsA1 = As + 2048 + wave * 512;
  unsigned short* ldsB0 = Bs + wave * 512;
  unsigned short* ldsB1 = Bs + 2048 + wave * 512;

  const int fr = lane & 15;         // fragment row
  const int fk = (lane >> 4) * 8;   // fragment k offset

  for (int k0 = 0; k0 < DIM; k0 += 32) {
    const unsigned short* gA0 = FB + (size_t)(brow + s_r) * DIM + (k0 + s_c);
    const unsigned short* gA1 = FB + (size_t)(brow + 64 + s_r) * DIM + (k0 + s_c);
    const unsigned short* gB0 = FB + (size_t)(bcol + s_r) * DIM + (k0 + s_c);
    const unsigned short* gB1 = FB + (size_t)(bcol + 64 + s_r) * DIM + (k0 + s_c);
    __builtin_amdgcn_global_load_lds((const __attribute__((address_space(1))) unsigned int*)gA0,
                                     (__attribute__((address_space(3))) unsigned int*)ldsA0, 16, 0, 0);
    __builtin_amdgcn_global_load_lds((const __attribute__((address_space(1))) unsigned int*)gA1,
                                     (__attribute__((address_space(3))) unsigned int*)ldsA1, 16, 0, 0);
    __builtin_amdgcn_global_load_lds((const __attribute__((address_space(1))) unsigned int*)gB0,
                                     (__attribute__((address_space(3))) unsigned int*)ldsB0, 16, 0, 0);
    __builtin_amdgcn_global_load_lds((const __attribute__((address_space(1))) unsigned int*)gB1,
                                     (__attribute__((address_space(3))) unsigned int*)ldsB1, 16, 0, 0);
    __syncthreads();  // drains vmcnt -> staged data visible

    bf16x8 af[4], bg[4];
#pragma unroll
    for (int m = 0; m < 4; ++m)
      af[m] = *(const bf16x8*)&As[(wr * 64 + m * 16 + fr) * 32 + fk];
#pragma unroll
    for (int n = 0; n < 4; ++n)
      bg[n] = *(const bf16x8*)&Bs[(wc * 64 + n * 16 + fr) * 32 + fk];
#pragma unroll
    for (int m = 0; m < 4; ++m)
#pragma unroll
      for (int n = 0; n < 4; ++n)
        acc[m][n] = __builtin_amdgcn_mfma_f32_16x16x32_bf16(af[m], bg[n], acc[m][n], 0, 0, 0);
    __syncthreads();  // all reads done before next stage overwrites
  }

  const int rsub = (lane >> 4) * 4;
#pragma unroll
  for (int m = 0; m < 4; ++m)
#pragma unroll
    for (int n = 0; n < 4; ++n) {
      const int r0 = brow + wr * 64 + m * 16 + rsub;
      const int c  = bcol + wc * 64 + n * 16 + fr;
#pragma unroll
      for (int i = 0; i < 4; ++i)
        C[(size_t)(r0 + i) * NROW + c] = acc[m][n][i] * TEMP_INV;
    }
}

// ---------------- Kernel 3: per-row hard mining + loss ----------------
__global__ __launch_bounds__(256) void row_loss_k(const float* __restrict__ S,
                                                  const int* __restrict__ labels,
                                                  float* __restrict__ out) {
  __shared__ float srow[NROW];              // 16 KB
  __shared__ unsigned char flag[NROW];      // 4 KB: 0=self 1=pos 2=neg
  __shared__ unsigned int hist[256];
  __shared__ unsigned int ssum[256];
  __shared__ int cnt_pos_s, cnt_neg_s;
  __shared__ unsigned int sel_bin_s, sel_rem_s;
  __shared__ float partials[16];

  const int i = blockIdx.x;
  const int tid = threadIdx.x;
  const int my_label = labels[i];

  if (tid == 0) { cnt_pos_s = 0; cnt_neg_s = 0; }

  int lp = 0, ln = 0;
  for (int j = tid; j < NROW; j += 256) {
    float v = S[(size_t)i * NROW + j];
    srow[j] = v;
    int lj = labels[j];
    unsigned char f = (j == i) ? 0 : ((lj == my_label) ? 1 : 2);
    flag[j] = f;
    lp += (f == 1);
    ln += (f == 2);
  }
  __syncthreads();  // init visible + srow/flag complete
  atomicAdd(&cnt_pos_s, lp);
  atomicAdd(&cnt_neg_s, ln);
  __syncthreads();

  const int count = cnt_neg_s;
  int k = (int)((float)count * 0.5f);  // matches ref: floor(count*0.5)
  if (k < 1) k = 1;

  // 4-level radix select (8 bits/level, descending) over negative keys
  unsigned key_prefix = 0;
  int remaining = k;
  for (int level = 0; level < 4; ++level) {
    const int shift = 24 - level * 8;
    hist[tid] = 0;
    __syncthreads();
    for (int j = tid; j < NROW; j += 256) {
      if (flag[j] == 2) {
        unsigned key = mono_key(srow[j]);
        bool ok = (level == 0) || ((key >> (shift + 8)) == (key_prefix >> (shift + 8)));
        if (ok) atomicAdd(&hist[(key >> shift) & 255u], 1u);
      }
    }
    __syncthreads();
    ssum[tid] = hist[tid];
    __syncthreads();
    for (int off = 1; off < 256; off <<= 1) {   // suffix sum
      unsigned add = (tid + off < 256) ? ssum[tid + off] : 0u;
      __syncthreads();
      ssum[tid] += add;
      __syncthreads();
    }
    unsigned Sb  = ssum[tid];
    unsigned Sb1 = (tid < 255) ? ssum[tid + 1] : 0u;
    if ((int)Sb >= remaining && (int)Sb1 < remaining) {
      sel_bin_s = (unsigned)tid;
      sel_rem_s = (unsigned)remaining - Sb1;
    }
    __syncthreads();
    key_prefix |= (sel_bin_s << shift);
    remaining = (int)sel_rem_s;
    __syncthreads();
  }

  const float thr = inv_key(key_prefix);  // exact k-th largest negative sim

  // fused final pass
  float negexp = 0.f, possum = 0.f, selfv = 0.f;
  int pc_local = 0;
  for (int j = tid; j < NROW; j += 256) {
    float v = srow[j];
    unsigned char f = flag[j];
    if (f == 2) {
      if (v >= thr) negexp += expf(v);
    } else if (f == 1) {
      possum += v;
      pc_local++;
    } else {
      selfv = v;  // j == i, exactly one thread
    }
  }
  negexp = wave_sum_f(negexp);
  possum = wave_sum_f(possum);
  selfv  = wave_sum_f(selfv);
  float pcf = wave_sum_f((float)pc_local);
  const int w = tid >> 6;
  if ((tid & 63) == 0) {
    partials[w]      = negexp;
    partials[4 + w]  = possum;
    partials[8 + w]  = selfv;
    partials[12 + w] = pcf;
  }
  __syncthreads();
  if (tid == 0) {
    float ne = partials[0] + partials[1] + partials[2] + partials[3];
    float ps = partials[4] + partials[5] + partials[6] + partials[7];
    float sv = partials[8] + partials[9] + partials[10] + partials[11];
    float pc = partials[12] + partials[13] + partials[14] + partials[15];
    float denom = ne + expf(sv) + 1e-10f;
    float logd = logf(denom);
    float mlpp = (ps - pc * logd) / (pc + 1e-10f);
    atomicAdd(out, -mlpp * (1.0f / (float)NROW));
  }
}

// ---------------- launcher ----------------
extern "C" void kernel_launch(void* const* d_in, const int* in_sizes, int n_in,
                              void* d_out, int out_size, void* d_ws, size_t ws_size,
                              hipStream_t stream) {
  const float* X    = (const float*)d_in[0];
  const int* labels = (const int*)d_in[1];
  float* out        = (float*)d_out;

  unsigned short* FB = (unsigned short*)d_ws;                       // 8 MB bf16
  float* S = (float*)((char*)d_ws + (size_t)NROW * DIM * 2);        // 64 MB f32

  hipMemsetAsync(out, 0, sizeof(float), stream);
  normalize_k<<<NROW, 256, 0, stream>>>(X, FB);
  dim3 g(NROW / 128, NROW / 128);
  gemm_sim<<<g, 256, 0, stream>>>(FB, S);
  row_loss_k<<<NROW, 256, 0, stream>>>(S, labels, out);
}

// Round 3
// 170.864 us; speedup vs baseline: 1.4376x; 1.4376x over previous
//
#include <hip/hip_runtime.h>

#define NROW 4096
#define DIM  1024
#define TEMP_INV 14.285714285714286f /* 1/0.07 */

typedef __attribute__((ext_vector_type(8))) short bf16x8;
typedef __attribute__((ext_vector_type(4))) float f32x4;

__device__ __forceinline__ unsigned f2bf_u(float f) {
  unsigned u = __float_as_uint(f);
  return (u + 0x7FFFu + ((u >> 16) & 1u)) >> 16;  // RNE bf16
}

__device__ __forceinline__ float wave_sum_f(float v) {
#pragma unroll
  for (int off = 32; off > 0; off >>= 1) v += __shfl_down(v, off);
  return v;
}

__device__ __forceinline__ unsigned mono_key(float x) {
  unsigned u = __float_as_uint(x);
  return (u & 0x80000000u) ? ~u : (u | 0x80000000u);
}
__device__ __forceinline__ float inv_key(unsigned k) {
  return __uint_as_float((k & 0x80000000u) ? (k ^ 0x80000000u) : ~k);
}

// ---------------- Kernel 1: L2 normalize rows, emit bf16 ----------------
__global__ __launch_bounds__(256) void normalize_k(const float* __restrict__ X,
                                                   unsigned short* __restrict__ FB) {
  __shared__ float warp_s[4];
  const int row = blockIdx.x;
  const int tid = threadIdx.x;
  const float4* x4 = (const float4*)(X + (size_t)row * DIM);
  float4 v = x4[tid];  // 256 threads * 4 = 1024
  float ss = v.x * v.x + v.y * v.y + v.z * v.z + v.w * v.w;
  ss = wave_sum_f(ss);
  if ((tid & 63) == 0) warp_s[tid >> 6] = ss;
  __syncthreads();
  float total = warp_s[0] + warp_s[1] + warp_s[2] + warp_s[3];
  float inv = 1.0f / fmaxf(sqrtf(total), 1e-12f);
  ushort4 o;
  o.x = (unsigned short)f2bf_u(v.x * inv);
  o.y = (unsigned short)f2bf_u(v.y * inv);
  o.z = (unsigned short)f2bf_u(v.z * inv);
  o.w = (unsigned short)f2bf_u(v.w * inv);
  ((ushort4*)(FB + (size_t)row * DIM))[tid] = o;
}

// ---------------- Kernel 2: sim = (FB @ FB^T) * (1/T), f32 out ----------------
// 128x128 tile, BK=32, 4 waves each owning a 64x64 subtile, 16x16x32 bf16 MFMA.
// (unchanged from round 2 — known correct; 8-phase rewrite is next round's target)
__global__ __launch_bounds__(256) void gemm_sim(const unsigned short* __restrict__ FB,
                                                float* __restrict__ C) {
  __shared__ unsigned short As[128 * 32] __attribute__((aligned(16)));
  __shared__ unsigned short Bs[128 * 32] __attribute__((aligned(16)));
  const int tid  = threadIdx.x;
  const int wave = tid >> 6;
  const int lane = tid & 63;
  const int wr = wave >> 1;  // wave row 0..1
  const int wc = wave & 1;   // wave col 0..1
  const int brow = blockIdx.y * 128;
  const int bcol = blockIdx.x * 128;

  f32x4 acc[4][4];
#pragma unroll
  for (int m = 0; m < 4; ++m)
#pragma unroll
    for (int n = 0; n < 4; ++n) acc[m][n] = (f32x4){0.f, 0.f, 0.f, 0.f};

  const int s_r = wave * 16 + (lane >> 2);
  const int s_c = (lane & 3) * 8;
  unsigned short* ldsA0 = As + wave * 512;
  unsigned short* ldsA1 = As + 2048 + wave * 512;
  unsigned short* ldsB0 = Bs + wave * 512;
  unsigned short* ldsB1 = Bs + 2048 + wave * 512;

  const int fr = lane & 15;         // fragment row
  const int fk = (lane >> 4) * 8;   // fragment k offset

  for (int k0 = 0; k0 < DIM; k0 += 32) {
    const unsigned short* gA0 = FB + (size_t)(brow + s_r) * DIM + (k0 + s_c);
    const unsigned short* gA1 = FB + (size_t)(brow + 64 + s_r) * DIM + (k0 + s_c);
    const unsigned short* gB0 = FB + (size_t)(bcol + s_r) * DIM + (k0 + s_c);
    const unsigned short* gB1 = FB + (size_t)(bcol + 64 + s_r) * DIM + (k0 + s_c);
    __builtin_amdgcn_global_load_lds((const __attribute__((address_space(1))) unsigned int*)gA0,
                                     (__attribute__((address_space(3))) unsigned int*)ldsA0, 16, 0, 0);
    __builtin_amdgcn_global_load_lds((const __attribute__((address_space(1))) unsigned int*)gA1,
                                     (__attribute__((address_space(3))) unsigned int*)ldsA1, 16, 0, 0);
    __builtin_amdgcn_global_load_lds((const __attribute__((address_space(1))) unsigned int*)gB0,
                                     (__attribute__((address_space(3))) unsigned int*)ldsB0, 16, 0, 0);
    __builtin_amdgcn_global_load_lds((const __attribute__((address_space(1))) unsigned int*)gB1,
                                     (__attribute__((address_space(3))) unsigned int*)ldsB1, 16, 0, 0);
    __syncthreads();  // drains vmcnt -> staged data visible

    bf16x8 af[4], bg[4];
#pragma unroll
    for (int m = 0; m < 4; ++m)
      af[m] = *(const bf16x8*)&As[(wr * 64 + m * 16 + fr) * 32 + fk];
#pragma unroll
    for (int n = 0; n < 4; ++n)
      bg[n] = *(const bf16x8*)&Bs[(wc * 64 + n * 16 + fr) * 32 + fk];
#pragma unroll
    for (int m = 0; m < 4; ++m)
#pragma unroll
      for (int n = 0; n < 4; ++n)
        acc[m][n] = __builtin_amdgcn_mfma_f32_16x16x32_bf16(af[m], bg[n], acc[m][n], 0, 0, 0);
    __syncthreads();  // all reads done before next stage overwrites
  }

  const int rsub = (lane >> 4) * 4;
#pragma unroll
  for (int m = 0; m < 4; ++m)
#pragma unroll
    for (int n = 0; n < 4; ++n) {
      const int r0 = brow + wr * 64 + m * 16 + rsub;
      const int c  = bcol + wc * 64 + n * 16 + fr;
#pragma unroll
      for (int i = 0; i < 4; ++i)
        C[(size_t)(r0 + i) * NROW + c] = acc[m][n][i] * TEMP_INV;
    }
}

// ---------------- Kernel 3: per-row hard mining + loss ----------------
// One WAVE per row, 4 waves/block, ZERO __syncthreads. Row lives in registers
// (16 x float4 / lane); exact 4x8-bit radix select with per-wave LDS histogram
// (wave-internal lgkmcnt fences only) and shfl-based 256-bin suffix scan.
__global__ __launch_bounds__(256) void row_loss_k(const float* __restrict__ S,
                                                  const int* __restrict__ labels,
                                                  float* __restrict__ row_out) {
  __shared__ unsigned hist[4][256] __attribute__((aligned(16)));
  const int wave = threadIdx.x >> 6;
  const int lane = threadIdx.x & 63;
  const int row  = blockIdx.x * 4 + wave;
  const int my   = labels[row];

  // element (e,c) of this lane is column j = e*256 + lane*4 + c
  float4 d[16];
  const float4* rp = (const float4*)(S + (size_t)row * NROW);
  const int4*   lp = (const int4*)labels;
#pragma unroll
  for (int e = 0; e < 16; ++e) d[e] = rp[e * 64 + lane];

  unsigned long long negm = 0ull, posm = 0ull;
#pragma unroll
  for (int e = 0; e < 16; ++e) {
    int4 lb = lp[e * 64 + lane];
    const int j0 = e * 256 + lane * 4;
    if (lb.x != my) negm |= 1ull << (e * 4 + 0); else if (j0 + 0 != row) posm |= 1ull << (e * 4 + 0);
    if (lb.y != my) negm |= 1ull << (e * 4 + 1); else if (j0 + 1 != row) posm |= 1ull << (e * 4 + 1);
    if (lb.z != my) negm |= 1ull << (e * 4 + 2); else if (j0 + 2 != row) posm |= 1ull << (e * 4 + 2);
    if (lb.w != my) negm |= 1ull << (e * 4 + 3); else if (j0 + 3 != row) posm |= 1ull << (e * 4 + 3);
  }

  int nneg = __popcll(negm);
#pragma unroll
  for (int off = 32; off > 0; off >>= 1) nneg += __shfl_xor(nneg, off);
  int k = nneg >> 1;            // floor(count*0.5), exact
  if (k < 1) k = 1;

  unsigned prefix = 0;
  int rem = k;
#pragma unroll
  for (int level = 0; level < 4; ++level) {
    const int shift = 24 - level * 8;
    *(uint4*)&hist[wave][lane * 4] = (uint4){0u, 0u, 0u, 0u};
    asm volatile("s_waitcnt lgkmcnt(0)" ::: "memory");  // zeros visible wave-wide
#pragma unroll
    for (int e = 0; e < 16; ++e) {
#pragma unroll
      for (int c = 0; c < 4; ++c) {
        const int idx = e * 4 + c;
        float v = ((const float*)&d[e])[c];  // static after unroll
        unsigned key = mono_key(v);
        bool isneg = (negm >> idx) & 1ull;
        bool ok = isneg && (level == 0 || (key >> (shift + 8)) == (prefix >> (shift + 8)));
        if (ok) atomicAdd(&hist[wave][(key >> shift) & 255u], 1u);
      }
    }
    asm volatile("s_waitcnt lgkmcnt(0)" ::: "memory");  // atomics visible wave-wide
    uint4 h = *(const uint4*)&hist[wave][lane * 4];
    int ts = (int)(h.x + h.y + h.z + h.w);
#pragma unroll
    for (int off = 1; off < 64; off <<= 1) {            // suffix scan across lanes
      int v = __shfl_down(ts, off);
      ts += (lane + off < 64) ? v : 0;
    }
    int tnext = __shfl_down(ts, 1);
    if (lane == 63) tnext = 0;
    const int S0 = ts;                 // suffix sum from bin 4*lane
    const int S1 = S0 - (int)h.x;
    const int S2 = S1 - (int)h.y;
    const int S3 = S2 - (int)h.z;
    const int S4 = tnext;
    int bin = -1, nrem = 0;
    if      (S0 >= rem && S1 < rem) { bin = lane * 4 + 0; nrem = rem - S1; }
    else if (S1 >= rem && S2 < rem) { bin = lane * 4 + 1; nrem = rem - S2; }
    else if (S2 >= rem && S3 < rem) { bin = lane * 4 + 2; nrem = rem - S3; }
    else if (S3 >= rem && S4 < rem) { bin = lane * 4 + 3; nrem = rem - S4; }
    unsigned long long m = __ballot(bin >= 0);
    if (m) {                            // wave-uniform; m==0 only if no negatives
      int src = __ffsll((unsigned long long)m) - 1;
      bin  = __shfl(bin, src);
      nrem = __shfl(nrem, src);
      prefix |= ((unsigned)bin) << shift;
      rem = nrem;
    }
  }
  const float thr = inv_key(prefix);    // exact k-th largest negative sim

  float negexp = 0.f, possum = 0.f, selfv = 0.f;
  int pc = 0;
#pragma unroll
  for (int e = 0; e < 16; ++e) {
#pragma unroll
    for (int c = 0; c < 4; ++c) {
      const int idx = e * 4 + c;
      const int j = e * 256 + lane * 4 + c;
      float v = ((const float*)&d[e])[c];
      bool isneg = (negm >> idx) & 1ull;
      negexp += __expf((isneg && v >= thr) ? v : -1e30f);  // exp(-1e30)->0
      if ((posm >> idx) & 1ull) { possum += v; pc++; }
      if (j == row) selfv = v;
    }
  }
#pragma unroll
  for (int off = 32; off > 0; off >>= 1) {
    negexp += __shfl_xor(negexp, off);
    possum += __shfl_xor(possum, off);
    selfv  += __shfl_xor(selfv, off);
    pc     += __shfl_xor(pc, off);
  }
  if (lane == 0) {
    float denom = negexp + expf(selfv) + 1e-10f;
    float logd = logf(denom);
    row_out[row] = (possum - (float)pc * logd) / ((float)pc + 1e-10f);
  }
}

// ---------------- Kernel 4: reduce per-row losses -> scalar ----------------
__global__ __launch_bounds__(256) void final_reduce_k(const float* __restrict__ row_out,
                                                      float* __restrict__ out) {
  __shared__ float ws[4];
  float s = 0.f;
  const float4* rp = (const float4*)row_out;
#pragma unroll
  for (int e = 0; e < 4; ++e) {
    float4 v = rp[e * 256 + threadIdx.x];
    s += v.x + v.y + v.z + v.w;
  }
#pragma unroll
  for (int off = 32; off > 0; off >>= 1) s += __shfl_xor(s, off);
  if ((threadIdx.x & 63) == 0) ws[threadIdx.x >> 6] = s;
  __syncthreads();
  if (threadIdx.x == 0) out[0] = -(ws[0] + ws[1] + ws[2] + ws[3]) * (1.0f / (float)NROW);
}

// ---------------- launcher ----------------
extern "C" void kernel_launch(void* const* d_in, const int* in_sizes, int n_in,
                              void* d_out, int out_size, void* d_ws, size_t ws_size,
                              hipStream_t stream) {
  const float* X    = (const float*)d_in[0];
  const int* labels = (const int*)d_in[1];
  float* out        = (float*)d_out;

  unsigned short* FB = (unsigned short*)d_ws;                       // 8 MB bf16
  float* S = (float*)((char*)d_ws + (size_t)NROW * DIM * 2);        // 64 MB f32
  // per-row losses reuse the FB region (dead after gemm_sim completes)
  float* row_out = (float*)d_ws;

  normalize_k<<<NROW, 256, 0, stream>>>(X, FB);
  dim3 g(NROW / 128, NROW / 128);
  gemm_sim<<<g, 256, 0, stream>>>(FB, S);
  row_loss_k<<<NROW / 4, 256, 0, stream>>>(S, labels, row_out);
  final_reduce_k<<<1, 256, 0, stream>>>(row_out, out);
}

// Round 5
// 169.861 us; speedup vs baseline: 1.4461x; 1.0059x over previous
//
#include <hip/hip_runtime.h>

#define NROW 4096
#define DIM  1024
#define TEMP_INV 14.285714285714286f /* 1/0.07 */
#define NBINS 2048
#define HSLOTS 2304  /* 2048 bins + 4-word pad per 32: slot(b) = b + ((b>>5)<<2) */

typedef __attribute__((ext_vector_type(8))) short bf16x8;
typedef __attribute__((ext_vector_type(4))) float f32x4;

__device__ __forceinline__ unsigned f2bf_u(float f) {
  unsigned u = __float_as_uint(f);
  return (u + 0x7FFFu + ((u >> 16) & 1u)) >> 16;  // RNE bf16
}

__device__ __forceinline__ float wave_sum_f(float v) {
#pragma unroll
  for (int off = 32; off > 0; off >>= 1) v += __shfl_down(v, off);
  return v;
}

// ---------------- Kernel 1: L2 normalize rows, emit bf16 ----------------
__global__ __launch_bounds__(256) void normalize_k(const float* __restrict__ X,
                                                   unsigned short* __restrict__ FB) {
  __shared__ float warp_s[4];
  const int row = blockIdx.x;
  const int tid = threadIdx.x;
  const float4* x4 = (const float4*)(X + (size_t)row * DIM);
  float4 v = x4[tid];  // 256 threads * 4 = 1024
  float ss = v.x * v.x + v.y * v.y + v.z * v.z + v.w * v.w;
  ss = wave_sum_f(ss);
  if ((tid & 63) == 0) warp_s[tid >> 6] = ss;
  __syncthreads();
  float total = warp_s[0] + warp_s[1] + warp_s[2] + warp_s[3];
  float inv = 1.0f / fmaxf(sqrtf(total), 1e-12f);
  ushort4 o;
  o.x = (unsigned short)f2bf_u(v.x * inv);
  o.y = (unsigned short)f2bf_u(v.y * inv);
  o.z = (unsigned short)f2bf_u(v.z * inv);
  o.w = (unsigned short)f2bf_u(v.w * inv);
  ((ushort4*)(FB + (size_t)row * DIM))[tid] = o;
}

// ---------------- Kernel 2: sim = (FB @ FB^T) * (1/T), f32 out ----------------
// 128x128 tile, BK=32, 4 waves each owning a 64x64 subtile, 16x16x32 bf16 MFMA.
// (unchanged — must be <58 us per the round-3 profile; rewrite once counters land)
__global__ __launch_bounds__(256) void gemm_sim(const unsigned short* __restrict__ FB,
                                                float* __restrict__ C) {
  __shared__ unsigned short As[128 * 32] __attribute__((aligned(16)));
  __shared__ unsigned short Bs[128 * 32] __attribute__((aligned(16)));
  const int tid  = threadIdx.x;
  const int wave = tid >> 6;
  const int lane = tid & 63;
  const int wr = wave >> 1;  // wave row 0..1
  const int wc = wave & 1;   // wave col 0..1
  const int brow = blockIdx.y * 128;
  const int bcol = blockIdx.x * 128;

  f32x4 acc[4][4];
#pragma unroll
  for (int m = 0; m < 4; ++m)
#pragma unroll
    for (int n = 0; n < 4; ++n) acc[m][n] = (f32x4){0.f, 0.f, 0.f, 0.f};

  const int s_r = wave * 16 + (lane >> 2);
  const int s_c = (lane & 3) * 8;
  unsigned short* ldsA0 = As + wave * 512;
  unsigned short* ldsA1 = As + 2048 + wave * 512;
  unsigned short* ldsB0 = Bs + wave * 512;
  unsigned short* ldsB1 = Bs + 2048 + wave * 512;

  const int fr = lane & 15;         // fragment row
  const int fk = (lane >> 4) * 8;   // fragment k offset

  for (int k0 = 0; k0 < DIM; k0 += 32) {
    const unsigned short* gA0 = FB + (size_t)(brow + s_r) * DIM + (k0 + s_c);
    const unsigned short* gA1 = FB + (size_t)(brow + 64 + s_r) * DIM + (k0 + s_c);
    const unsigned short* gB0 = FB + (size_t)(bcol + s_r) * DIM + (k0 + s_c);
    const unsigned short* gB1 = FB + (size_t)(bcol + 64 + s_r) * DIM + (k0 + s_c);
    __builtin_amdgcn_global_load_lds((const __attribute__((address_space(1))) unsigned int*)gA0,
                                     (__attribute__((address_space(3))) unsigned int*)ldsA0, 16, 0, 0);
    __builtin_amdgcn_global_load_lds((const __attribute__((address_space(1))) unsigned int*)gA1,
                                     (__attribute__((address_space(3))) unsigned int*)ldsA1, 16, 0, 0);
    __builtin_amdgcn_global_load_lds((const __attribute__((address_space(1))) unsigned int*)gB0,
                                     (__attribute__((address_space(3))) unsigned int*)ldsB0, 16, 0, 0);
    __builtin_amdgcn_global_load_lds((const __attribute__((address_space(1))) unsigned int*)gB1,
                                     (__attribute__((address_space(3))) unsigned int*)ldsB1, 16, 0, 0);
    __syncthreads();  // drains vmcnt -> staged data visible

    bf16x8 af[4], bg[4];
#pragma unroll
    for (int m = 0; m < 4; ++m)
      af[m] = *(const bf16x8*)&As[(wr * 64 + m * 16 + fr) * 32 + fk];
#pragma unroll
    for (int n = 0; n < 4; ++n)
      bg[n] = *(const bf16x8*)&Bs[(wc * 64 + n * 16 + fr) * 32 + fk];
#pragma unroll
    for (int m = 0; m < 4; ++m)
#pragma unroll
      for (int n = 0; n < 4; ++n)
        acc[m][n] = __builtin_amdgcn_mfma_f32_16x16x32_bf16(af[m], bg[n], acc[m][n], 0, 0, 0);
    __syncthreads();  // all reads done before next stage overwrites
  }

  const int rsub = (lane >> 4) * 4;
#pragma unroll
  for (int m = 0; m < 4; ++m)
#pragma unroll
    for (int n = 0; n < 4; ++n) {
      const int r0 = brow + wr * 64 + m * 16 + rsub;
      const int c  = bcol + wc * 64 + n * 16 + fr;
#pragma unroll
      for (int i = 0; i < 4; ++i)
        C[(size_t)(r0 + i) * NROW + c] = acc[m][n][i] * TEMP_INV;
    }
}

// ---------------- Kernel 3: per-row hard mining + loss ----------------
// One WAVE per row, zero __syncthreads. Row in registers (16 x float4/lane).
// Single fixed-range histogram select: sim is bounded (|sim| <= 1/0.07 < 16),
// bin = floor((v+16)*64) in [0,2048). Threshold = lower edge of the bin holding
// the k-th largest negative; selection by (bin >= B) is count-consistent.
// Error vs exact topk <= elems-in-threshold-bin (~57) * e^thr (~1) against
// denom ~1.6e6 -> Delta(loss) ~3.5e-5. Histogram padded (slot = b + (b>>5)*4)
// so per-lane scan reads are <=8-way bank-conflicted instead of 32-way.
__global__ __launch_bounds__(256) void row_loss_k(const float* __restrict__ S,
                                                  const int* __restrict__ labels,
                                                  float* __restrict__ row_out) {
  __shared__ unsigned hist[4][HSLOTS] __attribute__((aligned(16)));  // 36.9 KB
  const int wave = threadIdx.x >> 6;
  const int lane = threadIdx.x & 63;
  const int row  = blockIdx.x * 4 + wave;
  const int my   = labels[row];
  unsigned* H = hist[wave];

  // element (e,c) of this lane is column j = e*256 + lane*4 + c
  float4 d[16];
  const float4* rp = (const float4*)(S + (size_t)row * NROW);
  const int4*   lp = (const int4*)labels;
#pragma unroll
  for (int e = 0; e < 16; ++e) d[e] = rp[e * 64 + lane];

  // zero histogram: 2304 words / 64 lanes = 9 x uint4 per lane
#pragma unroll
  for (int z = 0; z < 9; ++z)
    *(uint4*)&H[z * 256 + lane * 4] = (uint4){0u, 0u, 0u, 0u};

  unsigned long long negm = 0ull, posm = 0ull;
#pragma unroll
  for (int e = 0; e < 16; ++e) {
    int4 lb = lp[e * 64 + lane];
    const int j0 = e * 256 + lane * 4;
    if (lb.x != my) negm |= 1ull << (e * 4 + 0); else if (j0 + 0 != row) posm |= 1ull << (e * 4 + 0);
    if (lb.y != my) negm |= 1ull << (e * 4 + 1); else if (j0 + 1 != row) posm |= 1ull << (e * 4 + 1);
    if (lb.z != my) negm |= 1ull << (e * 4 + 2); else if (j0 + 2 != row) posm |= 1ull << (e * 4 + 2);
    if (lb.w != my) negm |= 1ull << (e * 4 + 3); else if (j0 + 3 != row) posm |= 1ull << (e * 4 + 3);
  }

  int nneg = __popcll(negm);
#pragma unroll
  for (int off = 32; off > 0; off >>= 1) nneg += __shfl_xor(nneg, off);
  int k = nneg >> 1;            // floor(count*0.5)
  if (k < 1) k = 1;

  asm volatile("s_waitcnt lgkmcnt(0)" ::: "memory");  // zeros visible wave-wide

  // fill histogram (negatives only)
#pragma unroll
  for (int e = 0; e < 16; ++e) {
#pragma unroll
    for (int c = 0; c < 4; ++c) {
      const int idx = e * 4 + c;
      if ((negm >> idx) & 1ull) {
        float v = ((const float*)&d[e])[c];
        int b = (int)((v + 16.0f) * 64.0f);
        b = min(max(b, 0), NBINS - 1);
        atomicAdd(&H[b + ((b >> 5) << 2)], 1u);
      }
    }
  }
  asm volatile("s_waitcnt lgkmcnt(0)" ::: "memory");  // counts visible wave-wide

  // suffix scan: lane owns bins [lane*32, lane*32+32) at slots lane*36 + 0..31
  int ts = 0;
#pragma unroll
  for (int z = 0; z < 8; ++z) {
    uint4 h = *(const uint4*)&H[lane * 36 + z * 4];
    ts += (int)(h.x + h.y + h.z + h.w);
  }
  int sfx = ts;
#pragma unroll
  for (int off = 1; off < 64; off <<= 1) {
    int t = __shfl_down(sfx, off);
    sfx += (lane + off < 64) ? t : 0;
  }
  int snext = __shfl_down(sfx, 1);
  if (lane == 63) snext = 0;
  const bool iscross = (sfx >= k) && (snext < k);

  // in-lane descent from the top bin: find largest j with count(bin>=j) >= k
  int B = -1;
  int run = snext;
#pragma unroll
  for (int z = 7; z >= 0; --z) {
    uint4 h = *(const uint4*)&H[lane * 36 + z * 4];
    run += (int)h.w; if (B < 0 && run >= k) B = z * 4 + 3;
    run += (int)h.z; if (B < 0 && run >= k) B = z * 4 + 2;
    run += (int)h.y; if (B < 0 && run >= k) B = z * 4 + 1;
    run += (int)h.x; if (B < 0 && run >= k) B = z * 4 + 0;
  }
  B = iscross ? (lane * 32 + B) : -1;

  unsigned long long mB = __ballot(B >= 0);
  int Bsel = NBINS;  // sentinel: select none (no negatives)
  if (mB != 0ull) {
    int src = __ffsll(mB) - 1;
    Bsel = __shfl(B, src);
  }

  // fused final pass
  float negexp = 0.f, possum = 0.f, selfv = 0.f;
  int pc = 0;
#pragma unroll
  for (int e = 0; e < 16; ++e) {
#pragma unroll
    for (int c = 0; c < 4; ++c) {
      const int idx = e * 4 + c;
      const int j = e * 256 + lane * 4 + c;
      float v = ((const float*)&d[e])[c];
      int b = (int)((v + 16.0f) * 64.0f);
      bool sel = ((negm >> idx) & 1ull) && (b >= Bsel);
      negexp += __expf(sel ? v : -1e30f);  // exp(-1e30) -> 0
      if ((posm >> idx) & 1ull) { possum += v; pc++; }
      if (j == row) selfv = v;
    }
  }
#pragma unroll
  for (int off = 32; off > 0; off >>= 1) {
    negexp += __shfl_xor(negexp, off);
    possum += __shfl_xor(possum, off);
    selfv  += __shfl_xor(selfv, off);
    pc     += __shfl_xor(pc, off);
  }
  if (lane == 0) {
    float denom = negexp + expf(selfv) + 1e-10f;
    float logd = logf(denom);
    row_out[row] = (possum - (float)pc * logd) / ((float)pc + 1e-10f);
  }
}

// ---------------- Kernel 4: reduce per-row losses -> scalar ----------------
__global__ __launch_bounds__(256) void final_reduce_k(const float* __restrict__ row_out,
                                                      float* __restrict__ out) {
  __shared__ float ws[4];
  float s = 0.f;
  const float4* rp = (const float4*)row_out;
#pragma unroll
  for (int e = 0; e < 4; ++e) {
    float4 v = rp[e * 256 + threadIdx.x];
    s += v.x + v.y + v.z + v.w;
  }
#pragma unroll
  for (int off = 32; off > 0; off >>= 1) s += __shfl_xor(s, off);
  if ((threadIdx.x & 63) == 0) ws[threadIdx.x >> 6] = s;
  __syncthreads();
  if (threadIdx.x == 0) out[0] = -(ws[0] + ws[1] + ws[2] + ws[3]) * (1.0f / (float)NROW);
}

// ---------------- launcher ----------------
extern "C" void kernel_launch(void* const* d_in, const int* in_sizes, int n_in,
                              void* d_out, int out_size, void* d_ws, size_t ws_size,
                              hipStream_t stream) {
  const float* X    = (const float*)d_in[0];
  const int* labels = (const int*)d_in[1];
  float* out        = (float*)d_out;

  unsigned short* FB = (unsigned short*)d_ws;                       // 8 MB bf16
  float* S = (float*)((char*)d_ws + (size_t)NROW * DIM * 2);        // 64 MB f32
  // per-row losses reuse the FB region (dead after gemm_sim completes)
  float* row_out = (float*)d_ws;

  normalize_k<<<NROW, 256, 0, stream>>>(X, FB);
  dim3 g(NROW / 128, NROW / 128);
  gemm_sim<<<g, 256, 0, stream>>>(FB, S);
  row_loss_k<<<NROW / 4, 256, 0, stream>>>(S, labels, row_out);
  final_reduce_k<<<1, 256, 0, stream>>>(row_out, out);
}

// Round 6
// 139.505 us; speedup vs baseline: 1.7608x; 1.2176x over previous
//
#include <hip/hip_runtime.h>

#define NROW 4096
#define DIM  1024
#define TEMP_INV 14.285714285714286f /* 1/0.07 */
#define NBINS 2048
#define HSLOTS 2304  /* 2048 bins + 4-word pad per 32: slot(b) = b + ((b>>5)<<2) */

typedef __attribute__((ext_vector_type(8))) short bf16x8;
typedef __attribute__((ext_vector_type(4))) float f32x4;

__device__ __forceinline__ unsigned f2bf_u(float f) {
  unsigned u = __float_as_uint(f);
  return (u + 0x7FFFu + ((u >> 16) & 1u)) >> 16;  // RNE bf16
}

__device__ __forceinline__ float wave_sum_f(float v) {
#pragma unroll
  for (int off = 32; off > 0; off >>= 1) v += __shfl_down(v, off);
  return v;
}

// ---------------- Kernel 1: L2 normalize rows, emit bf16 ----------------
__global__ __launch_bounds__(256) void normalize_k(const float* __restrict__ X,
                                                   unsigned short* __restrict__ FB) {
  __shared__ float warp_s[4];
  const int row = blockIdx.x;
  const int tid = threadIdx.x;
  const float4* x4 = (const float4*)(X + (size_t)row * DIM);
  float4 v = x4[tid];  // 256 threads * 4 = 1024
  float ss = v.x * v.x + v.y * v.y + v.z * v.z + v.w * v.w;
  ss = wave_sum_f(ss);
  if ((tid & 63) == 0) warp_s[tid >> 6] = ss;
  __syncthreads();
  float total = warp_s[0] + warp_s[1] + warp_s[2] + warp_s[3];
  float inv = 1.0f / fmaxf(sqrtf(total), 1e-12f);
  ushort4 o;
  o.x = (unsigned short)f2bf_u(v.x * inv);
  o.y = (unsigned short)f2bf_u(v.y * inv);
  o.z = (unsigned short)f2bf_u(v.z * inv);
  o.w = (unsigned short)f2bf_u(v.w * inv);
  ((ushort4*)(FB + (size_t)row * DIM))[tid] = o;
}

// ---------------- Kernel 2: sim = (FB @ FB^T) * (1/T), f32 out ----------------
// 128x128 tile, BK=64, 4 waves each owning a 64x64 subtile, 16x16x32 bf16 MFMA.
// T2 XOR swizzle (rule 21: linear LDS dest for global_load_lds, inverse-swizzled
// GLOBAL source, swizzled ds_read): LDS[row][p] holds global[row][p ^ ((row&7)<<4)]
// (byte granularity, 16B units). ds_read_b128 lanes 0..15 (rows fr=0..15, same col)
// then hit 8 distinct 16B slots -> 2-way bank access (free, m136) instead of 8-way.
// T1: XCD-aware block swizzle (nwg=1024, %8==0 -> simple bijective form).
__global__ __launch_bounds__(256) void gemm_sim(const unsigned short* __restrict__ FB,
                                                float* __restrict__ C) {
  __shared__ unsigned short As[128 * 64] __attribute__((aligned(16)));  // 16 KB
  __shared__ unsigned short Bs[128 * 64] __attribute__((aligned(16)));  // 16 KB
  const int tid  = threadIdx.x;
  const int wave = tid >> 6;
  const int lane = tid & 63;
  const int wr = wave >> 1;  // wave row 0..1
  const int wc = wave & 1;   // wave col 0..1

  // T1: XCD swizzle over the 1024-block 1D grid (32x32 tiles)
  const int bid = blockIdx.x;
  const int swz = (bid & 7) * 128 + (bid >> 3);
  const int brow = (swz >> 5) * 128;
  const int bcol = (swz & 31) * 128;

  f32x4 acc[4][4];
#pragma unroll
  for (int m = 0; m < 4; ++m)
#pragma unroll
    for (int n = 0; n < 4; ++n) acc[m][n] = (f32x4){0.f, 0.f, 0.f, 0.f};

  // Staging: per array 16 KB = 4 gload_lds instrs (i=0..3), each covers 32 rows.
  // thread t: row_local = i*32 + wave*8 + (lane>>3); source col pre-swizzled:
  // colshort = ((lane&7) ^ (lane>>3)) * 8  (16B units XORed with row&7 == lane>>3).
  const int s_rl  = wave * 8 + (lane >> 3);              // + i*32
  const int s_cs  = (((lane & 7) ^ (lane >> 3)) << 3);   // shorts
  // ds_read swizzle precompute
  const int fr  = lane & 15;
  const int fk2 = (lane >> 4) << 4;       // byte offset of k-fragment: 0/16/32/48
  const int frx = (fr & 7) << 4;

  for (int k0 = 0; k0 < DIM; k0 += 64) {
#pragma unroll
    for (int i = 0; i < 4; ++i) {
      const int rl = i * 32 + s_rl;
      const unsigned short* gA = FB + (size_t)(brow + rl) * DIM + (k0 + s_cs);
      const unsigned short* gB = FB + (size_t)(bcol + rl) * DIM + (k0 + s_cs);
      unsigned short* lA = As + (i * 32 + wave * 8) * 64;  // wave-uniform base
      unsigned short* lB = Bs + (i * 32 + wave * 8) * 64;
      __builtin_amdgcn_global_load_lds((const __attribute__((address_space(1))) unsigned int*)gA,
                                       (__attribute__((address_space(3))) unsigned int*)lA, 16, 0, 0);
      __builtin_amdgcn_global_load_lds((const __attribute__((address_space(1))) unsigned int*)gB,
                                       (__attribute__((address_space(3))) unsigned int*)lB, 16, 0, 0);
    }
    __syncthreads();  // drains vmcnt -> staged data visible

#pragma unroll
    for (int h = 0; h < 2; ++h) {       // two K=32 halves of BK=64
      const int cb = ((fk2 + h * 64) ^ frx) >> 1;  // swizzled col (shorts)
      bf16x8 af[4], bg[4];
#pragma unroll
      for (int m = 0; m < 4; ++m)
        af[m] = *(const bf16x8*)&As[(wr * 64 + m * 16 + fr) * 64 + cb];
#pragma unroll
      for (int n = 0; n < 4; ++n)
        bg[n] = *(const bf16x8*)&Bs[(wc * 64 + n * 16 + fr) * 64 + cb];
#pragma unroll
      for (int m = 0; m < 4; ++m)
#pragma unroll
        for (int n = 0; n < 4; ++n)
          acc[m][n] = __builtin_amdgcn_mfma_f32_16x16x32_bf16(af[m], bg[n], acc[m][n], 0, 0, 0);
    }
    __syncthreads();  // all reads done before next stage overwrites
  }

  const int rsub = (lane >> 4) * 4;
#pragma unroll
  for (int m = 0; m < 4; ++m)
#pragma unroll
    for (int n = 0; n < 4; ++n) {
      const int r0 = brow + wr * 64 + m * 16 + rsub;
      const int c  = bcol + wc * 64 + n * 16 + fr;
#pragma unroll
      for (int i = 0; i < 4; ++i)
        C[(size_t)(r0 + i) * NROW + c] = acc[m][n][i] * TEMP_INV;
    }
}

// ---------------- Kernel 3: per-row hard mining + loss ----------------
// One WAVE per row, zero __syncthreads. VGPR-lean: the row is NOT kept resident
// (that cost 132 VGPR -> 2 waves/SIMD last round); it is re-read from L2/L3 in
// each phase. Single fixed-range histogram select (|sim| < 16, 2048 bins).
__global__ __launch_bounds__(256) void row_loss_k(const float* __restrict__ S,
                                                  const int* __restrict__ labels,
                                                  float* __restrict__ row_out) {
  __shared__ unsigned hist[4][HSLOTS] __attribute__((aligned(16)));  // 36.9 KB
  const int wave = threadIdx.x >> 6;
  const int lane = threadIdx.x & 63;
  const int row  = blockIdx.x * 4 + wave;
  const int my   = labels[row];
  unsigned* H = hist[wave];

  const float4* rp = (const float4*)(S + (size_t)row * NROW);
  const int4*   lp = (const int4*)labels;

  // zero histogram: 2304 words / 64 lanes = 9 x uint4 per lane
#pragma unroll
  for (int z = 0; z < 9; ++z)
    *(uint4*)&H[z * 256 + lane * 4] = (uint4){0u, 0u, 0u, 0u};

  // masks (labels only; element (e,c) is column j = e*256 + lane*4 + c)
  unsigned long long negm = 0ull, posm = 0ull;
#pragma unroll
  for (int e = 0; e < 16; ++e) {
    int4 lb = lp[e * 64 + lane];
    const int j0 = e * 256 + lane * 4;
    if (lb.x != my) negm |= 1ull << (e * 4 + 0); else if (j0 + 0 != row) posm |= 1ull << (e * 4 + 0);
    if (lb.y != my) negm |= 1ull << (e * 4 + 1); else if (j0 + 1 != row) posm |= 1ull << (e * 4 + 1);
    if (lb.z != my) negm |= 1ull << (e * 4 + 2); else if (j0 + 2 != row) posm |= 1ull << (e * 4 + 2);
    if (lb.w != my) negm |= 1ull << (e * 4 + 3); else if (j0 + 3 != row) posm |= 1ull << (e * 4 + 3);
  }

  int nneg = __popcll(negm);
#pragma unroll
  for (int off = 32; off > 0; off >>= 1) nneg += __shfl_xor(nneg, off);
  int k = nneg >> 1;            // floor(count*0.5)
  if (k < 1) k = 1;

  asm volatile("s_waitcnt lgkmcnt(0)" ::: "memory");  // zeros visible wave-wide

  // histogram fill pass (row streamed, not kept)
#pragma unroll 4
  for (int e = 0; e < 16; ++e) {
    float4 v4 = rp[e * 64 + lane];
#pragma unroll
    for (int c = 0; c < 4; ++c) {
      const int idx = e * 4 + c;
      if ((negm >> idx) & 1ull) {
        float v = ((const float*)&v4)[c];
        int b = (int)((v + 16.0f) * 64.0f);
        b = min(max(b, 0), NBINS - 1);
        atomicAdd(&H[b + ((b >> 5) << 2)], 1u);
      }
    }
  }
  asm volatile("s_waitcnt lgkmcnt(0)" ::: "memory");  // counts visible wave-wide

  // suffix scan: lane owns bins [lane*32, lane*32+32) at slots lane*36 + 0..31
  int ts = 0;
#pragma unroll
  for (int z = 0; z < 8; ++z) {
    uint4 h = *(const uint4*)&H[lane * 36 + z * 4];
    ts += (int)(h.x + h.y + h.z + h.w);
  }
  int sfx = ts;
#pragma unroll
  for (int off = 1; off < 64; off <<= 1) {
    int t = __shfl_down(sfx, off);
    sfx += (lane + off < 64) ? t : 0;
  }
  int snext = __shfl_down(sfx, 1);
  if (lane == 63) snext = 0;
  const bool iscross = (sfx >= k) && (snext < k);

  // in-lane descent: find largest bin B with count(bin >= B) >= k
  int B = -1;
  int run = snext;
#pragma unroll
  for (int z = 7; z >= 0; --z) {
    uint4 h = *(const uint4*)&H[lane * 36 + z * 4];
    run += (int)h.w; if (B < 0 && run >= k) B = z * 4 + 3;
    run += (int)h.z; if (B < 0 && run >= k) B = z * 4 + 2;
    run += (int)h.y; if (B < 0 && run >= k) B = z * 4 + 1;
    run += (int)h.x; if (B < 0 && run >= k) B = z * 4 + 0;
  }
  B = iscross ? (lane * 32 + B) : -1;

  unsigned long long mB = __ballot(B >= 0);
  int Bsel = NBINS;  // sentinel: select none (no negatives)
  if (mB != 0ull) {
    int src = __ffsll(mB) - 1;
    Bsel = __shfl(B, src);
  }

  // fused final pass (row streamed again; L2/L3-hot)
  float negexp = 0.f, possum = 0.f, selfv = 0.f;
  int pc = 0;
#pragma unroll 4
  for (int e = 0; e < 16; ++e) {
    float4 v4 = rp[e * 64 + lane];
#pragma unroll
    for (int c = 0; c < 4; ++c) {
      const int idx = e * 4 + c;
      const int j = e * 256 + lane * 4 + c;
      float v = ((const float*)&v4)[c];
      int b = (int)((v + 16.0f) * 64.0f);
      bool sel = ((negm >> idx) & 1ull) && (b >= Bsel);
      negexp += __expf(sel ? v : -1e30f);  // exp(-1e30) -> 0
      if ((posm >> idx) & 1ull) { possum += v; pc++; }
      if (j == row) selfv = v;
    }
  }
#pragma unroll
  for (int off = 32; off > 0; off >>= 1) {
    negexp += __shfl_xor(negexp, off);
    possum += __shfl_xor(possum, off);
    selfv  += __shfl_xor(selfv, off);
    pc     += __shfl_xor(pc, off);
  }
  if (lane == 0) {
    float denom = negexp + expf(selfv) + 1e-10f;
    float logd = logf(denom);
    row_out[row] = (possum - (float)pc * logd) / ((float)pc + 1e-10f);
  }
}

// ---------------- Kernel 4: reduce per-row losses -> scalar ----------------
__global__ __launch_bounds__(256) void final_reduce_k(const float* __restrict__ row_out,
                                                      float* __restrict__ out) {
  __shared__ float ws[4];
  float s = 0.f;
  const float4* rp = (const float4*)row_out;
#pragma unroll
  for (int e = 0; e < 4; ++e) {
    float4 v = rp[e * 256 + threadIdx.x];
    s += v.x + v.y + v.z + v.w;
  }
#pragma unroll
  for (int off = 32; off > 0; off >>= 1) s += __shfl_xor(s, off);
  if ((threadIdx.x & 63) == 0) ws[threadIdx.x >> 6] = s;
  __syncthreads();
  if (threadIdx.x == 0) out[0] = -(ws[0] + ws[1] + ws[2] + ws[3]) * (1.0f / (float)NROW);
}

// ---------------- launcher ----------------
extern "C" void kernel_launch(void* const* d_in, const int* in_sizes, int n_in,
                              void* d_out, int out_size, void* d_ws, size_t ws_size,
                              hipStream_t stream) {
  const float* X    = (const float*)d_in[0];
  const int* labels = (const int*)d_in[1];
  float* out        = (float*)d_out;

  unsigned short* FB = (unsigned short*)d_ws;                       // 8 MB bf16
  float* S = (float*)((char*)d_ws + (size_t)NROW * DIM * 2);        // 64 MB f32
  // per-row losses reuse the FB region (dead after gemm_sim completes)
  float* row_out = (float*)d_ws;

  normalize_k<<<NROW, 256, 0, stream>>>(X, FB);
  gemm_sim<<<1024, 256, 0, stream>>>(FB, S);
  row_loss_k<<<NROW / 4, 256, 0, stream>>>(S, labels, row_out);
  final_reduce_k<<<1, 256, 0, stream>>>(row_out, out);
}